// Round 19
// baseline (100.285 us; speedup 1.0000x reference)
//
#include <hip/hip_runtime.h>
#include <hip/hip_bf16.h>
#include <cstdint>
#include <cstddef>

constexpr int BB = 64;
constexpr int NN = 1024;
constexpr int DD = 256;
constexpr int PP = 256;

typedef short short8 __attribute__((ext_vector_type(8)));
typedef float f32x4 __attribute__((ext_vector_type(4)));

constexpr float LOG2E = 1.4426950408889634f;

__device__ __forceinline__ unsigned short f2bf(float f) {
    union { __hip_bfloat16 h; unsigned short u; } v;
    v.h = __float2bfloat16(f);
    return v.u;
}

// fast sigmoid: rcp(1 + exp2(-x*log2e))
__device__ __forceinline__ float fsigmoid(float x) {
    return __builtin_amdgcn_rcpf(1.f + __builtin_amdgcn_exp2f(x * -LOG2E));
}

__device__ __forceinline__ void pin8(short8& v) {
    asm volatile("" : "+v"(v));
}

// async global->LDS, 16B per lane, LDS dest = wave-uniform base + lane*16
__device__ __forceinline__ void async_load16(void* lds, const void* g) {
    __builtin_amdgcn_global_load_lds(
        (const __attribute__((address_space(1))) unsigned int*)g,
        (__attribute__((address_space(3))) unsigned int*)lds, 16, 0, 0);
}

// Stage a 256-row x 256-col bf16 tile (128KB) with 8 waves (32 rows/wave).
// XOR-swizzled via pre-swizzled SOURCE (LDS write stays linear).
__device__ __forceinline__ void stage256(const unsigned short* base,
                                         unsigned short* lds, int wv, int lane) {
    char* dst0 = (char*)lds + wv * 16384;
    #pragma unroll
    for (int i = 0; i < 16; i++) {
        int row = wv * 32 + i * 2 + (lane >> 5);
        int blk = (lane & 31) ^ (row & 7);
        async_load16(dst0 + i * 1024, (const char*)base + row * 512 + blk * 16);
    }
}

// Stage a 32-row x 256-col bf16 chunk (16KB) with 8 waves (4 rows/wave).
__device__ __forceinline__ void stage32_w8(const unsigned short* base,
                                           unsigned short* lds, int wv, int lane) {
    char* dst0 = (char*)lds + wv * 2048;
    #pragma unroll
    for (int i = 0; i < 2; i++) {
        int row = wv * 4 + i * 2 + (lane >> 5);
        int blk = (lane & 31) ^ (row & 7);
        async_load16(dst0 + i * 1024, (const char*)base + row * 512 + blk * 16);
    }
}

// Read a 16B MFMA fragment from a swizzled tile (row-stride 512B).
__device__ __forceinline__ short8 lds_frag(const unsigned short* lds, int row, int kidx) {
    uint32_t byte = (uint32_t)(row * 512) + (uint32_t)(((kidx ^ (row & 7)) & 31) << 4);
    return *reinterpret_cast<const short8*>(reinterpret_cast<const char*>(lds) + byte);
}

// ---- prep: wt[j][d] = bf16(w[d][j]) for j<256 -> w1, else w2 (transposed, bf16) ----
__global__ void prep_wt(const float* __restrict__ w1, const float* __restrict__ w2,
                        unsigned short* __restrict__ wt) {
    int j = blockIdx.x;        // 0..511
    int d = threadIdx.x;       // 0..255
    const float* w = (j < PP) ? w1 : w2;
    int jj = j & (PP - 1);
    wt[j * DD + d] = f2bf(w[d * PP + jj]);
}

// ---- q = sigmoid(x @ W1)  +  xv = x @ w4  (q-ONLY; k is computed inline in attn) ----
// 512-thr blocks (8 waves), grid 256 = 1 block/CU. W q-half (128KB) staged
// ONCE while x loads into regs (xf[2][8], 32 rows/wave); ONE barrier;
// barrier-free 16-pt sweep writes qb. (r13/r18 structure minus the k-half.)
__global__ __launch_bounds__(512, 2) void qk_fused(const float* __restrict__ x,
                                                   const unsigned short* __restrict__ wt,
                                                   const float* __restrict__ w4,
                                                   unsigned short* __restrict__ qb,
                                                   float* __restrict__ xv) {
    __shared__ __align__(16) unsigned short wl[256 * 256];   // 128KB, swizzled
    const int t = threadIdx.x, wv = t >> 6, lane = t & 63, l15 = lane & 15, l4 = lane >> 4;
    const int rowBase = blockIdx.x * 256 + wv * 32;

    stage256(wt, wl, wv, lane);   // q-half of W

    // hoist x fragments (bf16) + accumulate xv partials (f32) — overlaps stage
    short8 xf[2][8];
    float xvp[2] = {0.f, 0.f};
    #pragma unroll
    for (int kc = 0; kc < 8; kc++) {
        float4 w4a = *reinterpret_cast<const float4*>(w4 + kc * 32 + l4 * 8);
        float4 w4b = *reinterpret_cast<const float4*>(w4 + kc * 32 + l4 * 8 + 4);
        #pragma unroll
        for (int s = 0; s < 2; s++) {
            const float* xr = x + (size_t)(rowBase + s * 16 + l15) * DD + kc * 32 + l4 * 8;
            float4 a = *reinterpret_cast<const float4*>(xr);
            float4 b = *reinterpret_cast<const float4*>(xr + 4);
            xvp[s] += a.x * w4a.x + a.y * w4a.y + a.z * w4a.z + a.w * w4a.w
                    + b.x * w4b.x + b.y * w4b.y + b.z * w4b.z + b.w * w4b.w;
            short8 f;
            f[0] = (short)f2bf(a.x); f[1] = (short)f2bf(a.y);
            f[2] = (short)f2bf(a.z); f[3] = (short)f2bf(a.w);
            f[4] = (short)f2bf(b.x); f[5] = (short)f2bf(b.y);
            f[6] = (short)f2bf(b.z); f[7] = (short)f2bf(b.w);
            xf[s][kc] = f;
        }
    }
    #pragma unroll
    for (int s = 0; s < 2; s++)
        #pragma unroll
        for (int kc = 0; kc < 8; kc++) pin8(xf[s][kc]);
    #pragma unroll
    for (int s = 0; s < 2; s++) {
        xvp[s] += __shfl_xor(xvp[s], 16);
        xvp[s] += __shfl_xor(xvp[s], 32);
        if (l4 == 0) xv[rowBase + s * 16 + l15] = xvp[s];
    }

    __syncthreads();   // q-half of W ready

    #pragma unroll 1
    for (int pt = 0; pt < 16; pt++) {
        f32x4 acc0 = {0.f, 0.f, 0.f, 0.f};
        f32x4 acc1 = {0.f, 0.f, 0.f, 0.f};
        __builtin_amdgcn_s_setprio(1);
        #pragma unroll
        for (int kc = 0; kc < 8; kc++) {
            short8 wf = lds_frag(wl, pt * 16 + l15, kc * 4 + l4);
            acc0 = __builtin_amdgcn_mfma_f32_16x16x32_bf16(wf, xf[0][kc], acc0, 0, 0, 0);
            acc1 = __builtin_amdgcn_mfma_f32_16x16x32_bf16(wf, xf[1][kc], acc1, 0, 0, 0);
        }
        __builtin_amdgcn_s_setprio(0);
        // D: col(l15) = x-row, row(l4*4+r) = p-col
        const int pc = pt * 16 + l4 * 4;
        ushort4 pk;
        pk.x = f2bf(fsigmoid(acc0[0]));
        pk.y = f2bf(fsigmoid(acc0[1]));
        pk.z = f2bf(fsigmoid(acc0[2]));
        pk.w = f2bf(fsigmoid(acc0[3]));
        *reinterpret_cast<ushort4*>(qb + (size_t)(rowBase + l15) * PP + pc) = pk;
        pk.x = f2bf(fsigmoid(acc1[0]));
        pk.y = f2bf(fsigmoid(acc1[1]));
        pk.z = f2bf(fsigmoid(acc1[2]));
        pk.w = f2bf(fsigmoid(acc1[3]));
        *reinterpret_cast<ushort4*>(qb + (size_t)(rowBase + 16 + l15) * PP + pc) = pk;
    }
}

// ---- fused: K-quarter computed INLINE (x @ W2 -> sigmoid -> swizzled LDS),
//      then flash num/den over that quarter for all q of b ----
// 512-thr blocks (8 waves), 1-D grid 256, XCD-PINNED (wg&7 = b%8).
// Phase 1: wave holds xf[2][8] (32 m-rows); W2 streamed in 8x 16KB chunks;
//   D-fragments sigmoid'ed and ds_write_b64'ed at the EXACT inverse of
//   lds_frag's swizzle: byte = m*512 + (((p0>>3)^(m&7))<<4) + (p0&7)*2.
// Phase 2: unchanged r18 flash loop (qf[4][8] pinned, setprio MFMA cluster).
// Removes kb entirely (32MB HBM write + read).
__global__ __launch_bounds__(512, 2) void attn_logit(const float* __restrict__ x,
                                                     const unsigned short* __restrict__ wt,
                                                     const unsigned short* __restrict__ qb,
                                                     const float* __restrict__ xv,
                                                     float* __restrict__ numo,
                                                     float* __restrict__ deno) {
    __shared__ __align__(16) unsigned short kq[256 * 256];   // 128KB: K-quarter
    __shared__ __align__(16) unsigned short wld[32 * 256];   // 16KB: W2 chunk
    __shared__ float xvs[256];
    const int t = threadIdx.x, wv = t >> 6, lane = t & 63, l15 = lane & 15, l4 = lane >> 4;
    // XCD-pinned decode: wg = (b%8) + 8*(quarter + 4*(b/8))
    const int wg = blockIdx.x;
    const int xcd = wg & 7, r_ = wg >> 3;
    const int quarter = r_ & 3;
    const int b = xcd + 8 * (r_ >> 2);
    const unsigned short* wt2 = wt + 256 * DD;   // k-half of W

    stage32_w8(wt2, wld, wv, lane);   // W2 chunk 0

    // ---- phase 1 preamble: x fragments for this wave's 32 m-rows ----
    short8 xf[2][8];
    const float* xq = x + (size_t)(b * NN + quarter * 256 + wv * 32) * DD;
    #pragma unroll
    for (int kc = 0; kc < 8; kc++) {
        #pragma unroll
        for (int s = 0; s < 2; s++) {
            const float* xr = xq + (size_t)(s * 16 + l15) * DD + kc * 32 + l4 * 8;
            float4 a = *reinterpret_cast<const float4*>(xr);
            float4 bq = *reinterpret_cast<const float4*>(xr + 4);
            short8 f;
            f[0] = (short)f2bf(a.x);  f[1] = (short)f2bf(a.y);
            f[2] = (short)f2bf(a.z);  f[3] = (short)f2bf(a.w);
            f[4] = (short)f2bf(bq.x); f[5] = (short)f2bf(bq.y);
            f[6] = (short)f2bf(bq.z); f[7] = (short)f2bf(bq.w);
            xf[s][kc] = f;
        }
    }
    #pragma unroll
    for (int s = 0; s < 2; s++)
        #pragma unroll
        for (int kc = 0; kc < 8; kc++) pin8(xf[s][kc]);
    if (t < 256) xvs[t] = xv[b * NN + quarter * 256 + t];

    __syncthreads();   // chunk 0 staged

    // ---- phase 1: build K-quarter in LDS, 8 chunks of 32 p-cols ----
    #pragma unroll 1
    for (int c = 0; c < 8; c++) {
        __builtin_amdgcn_s_setprio(1);
        #pragma unroll
        for (int pt = 0; pt < 2; pt++) {
            f32x4 acc0 = {0.f, 0.f, 0.f, 0.f};
            f32x4 acc1 = {0.f, 0.f, 0.f, 0.f};
            #pragma unroll
            for (int kc = 0; kc < 8; kc++) {
                short8 wf = lds_frag(wld, pt * 16 + l15, kc * 4 + l4);
                acc0 = __builtin_amdgcn_mfma_f32_16x16x32_bf16(wf, xf[0][kc], acc0, 0, 0, 0);
                acc1 = __builtin_amdgcn_mfma_f32_16x16x32_bf16(wf, xf[1][kc], acc1, 0, 0, 0);
            }
            // D: col(l15) = m-row (x-row), row(l4*4+r) = p-col. Write into the
            // swizzled kq layout (inverse of lds_frag).
            const int p0 = c * 32 + pt * 16 + l4 * 4;
            #pragma unroll
            for (int s = 0; s < 2; s++) {
                const f32x4& a = s ? acc1 : acc0;
                ushort4 pk;
                pk.x = f2bf(fsigmoid(a[0]));
                pk.y = f2bf(fsigmoid(a[1]));
                pk.z = f2bf(fsigmoid(a[2]));
                pk.w = f2bf(fsigmoid(a[3]));
                int m = wv * 32 + s * 16 + l15;
                uint32_t byte = (uint32_t)(m * 512)
                              + (uint32_t)((((p0 >> 3) ^ (m & 7)) & 31) << 4)
                              + (uint32_t)((p0 & 7) * 2);
                *reinterpret_cast<ushort4*>(reinterpret_cast<char*>(kq) + byte) = pk;
            }
        }
        __builtin_amdgcn_s_setprio(0);
        __syncthreads();                  // wld reads done (+ final: K writes visible)
        if (c < 7) {
            stage32_w8(wt2 + (size_t)(c + 1) * 32 * DD, wld, wv, lane);
            __syncthreads();              // next chunk staged
        }
    }

    // ---- phase 2: flash num/den (r18 verbatim) ----
    #pragma unroll 1
    for (int p = 0; p < 2; p++) {
        short8 qf[4][8];
        const int q0 = b * NN + p * 512 + wv * 64;
        #pragma unroll
        for (int s = 0; s < 4; s++) {
            const unsigned short* qrow = qb + (size_t)(q0 + s * 16 + l15) * PP;
            #pragma unroll
            for (int kc = 0; kc < 8; kc++)
                qf[s][kc] = *reinterpret_cast<const short8*>(qrow + kc * 32 + l4 * 8);
        }
        #pragma unroll
        for (int s = 0; s < 4; s++)
            #pragma unroll
            for (int kc = 0; kc < 8; kc++) pin8(qf[s][kc]);

        float den[4][4], num[4][4];
        #pragma unroll
        for (int s = 0; s < 4; s++)
            #pragma unroll
            for (int r = 0; r < 4; r++) { den[s][r] = 0.f; num[s][r] = 0.f; }

        #pragma unroll 8
        for (int mc = 0; mc < 16; mc++) {
            f32x4 z = {0.f, 0.f, 0.f, 0.f};
            f32x4 a[4] = {z, z, z, z};
            __builtin_amdgcn_s_setprio(1);
            #pragma unroll
            for (int kc = 0; kc < 8; kc++) {
                short8 kf = lds_frag(kq, mc * 16 + l15, kc * 4 + l4);
                a[0] = __builtin_amdgcn_mfma_f32_16x16x32_bf16(qf[0][kc], kf, a[0], 0, 0, 0);
                a[1] = __builtin_amdgcn_mfma_f32_16x16x32_bf16(qf[1][kc], kf, a[1], 0, 0, 0);
                a[2] = __builtin_amdgcn_mfma_f32_16x16x32_bf16(qf[2][kc], kf, a[2], 0, 0, 0);
                a[3] = __builtin_amdgcn_mfma_f32_16x16x32_bf16(qf[3][kc], kf, a[3], 0, 0, 0);
            }
            __builtin_amdgcn_s_setprio(0);
            float xvv = xvs[mc * 16 + l15];
            #pragma unroll
            for (int s = 0; s < 4; s++)
                #pragma unroll
                for (int r = 0; r < 4; r++) {
                    // exp(s/16) = exp2(s * 0.0625*log2e); s in (0,16): no max-subtract
                    float e = __builtin_amdgcn_exp2f(a[s][r] * (0.0625f * LOG2E));
                    den[s][r] += e;
                    num[s][r] += e * xvv;
                }
        }
        #pragma unroll
        for (int s = 0; s < 4; s++)
            #pragma unroll
            for (int r = 0; r < 4; r++) {
                #pragma unroll
                for (int off = 1; off < 16; off <<= 1) {
                    den[s][r] += __shfl_xor(den[s][r], off);
                    num[s][r] += __shfl_xor(num[s][r], off);
                }
            }
        if (l15 == 0) {
            #pragma unroll
            for (int s = 0; s < 4; s++)
                #pragma unroll
                for (int r = 0; r < 4; r++) {
                    int n = p * 512 + wv * 64 + s * 16 + l4 * 4 + r;
                    size_t o = (size_t)quarter * BB * NN + (size_t)b * NN + n;
                    numo[o] = num[s][r];
                    deno[o] = den[s][r];
                }
        }
    }
}

// ---- sentence partials: merge 4 num/den quarters -> softmax_n -> weighted row sum ----
__global__ __launch_bounds__(256) void sent_partial(const float* __restrict__ x,
                                                    const float* __restrict__ numo,
                                                    const float* __restrict__ deno,
                                                    float* __restrict__ part) {
    __shared__ float al[64];
    __shared__ float redA[4];
    __shared__ float redB[4];
    const int b = blockIdx.x, ch = blockIdx.y;
    const int t = threadIdx.x;
    float l[4];
    #pragma unroll
    for (int i = 0; i < 4; i++) {
        int n = b * NN + t + i * 256;
        float ns = 0.f, ds = 0.f;
        #pragma unroll
        for (int q = 0; q < 4; q++) {
            ns += numo[(size_t)q * BB * NN + n];
            ds += deno[(size_t)q * BB * NN + n];
        }
        l[i] = ns / ds;
    }
    float mx = fmaxf(fmaxf(l[0], l[1]), fmaxf(l[2], l[3]));
    #pragma unroll
    for (int off = 1; off < 64; off <<= 1) mx = fmaxf(mx, __shfl_xor(mx, off));
    if ((t & 63) == 0) redA[t >> 6] = mx;
    __syncthreads();
    mx = fmaxf(fmaxf(redA[0], redA[1]), fmaxf(redA[2], redA[3]));
    float e[4], es = 0.f;
    #pragma unroll
    for (int i = 0; i < 4; i++) { e[i] = __expf(l[i] - mx); es += e[i]; }
    #pragma unroll
    for (int off = 1; off < 64; off <<= 1) es += __shfl_xor(es, off);
    if ((t & 63) == 0) redB[t >> 6] = es;
    __syncthreads();
    float inv = 1.f / (redB[0] + redB[1] + redB[2] + redB[3]);
    int ei = ch >> 2;
    float sel = (ei == 0) ? e[0] : (ei == 1) ? e[1] : (ei == 2) ? e[2] : e[3];
    if ((t >> 6) == (ch & 3)) al[t & 63] = sel * inv;
    __syncthreads();
    float acc = 0.f;
    const float* xb = x + ((size_t)b * NN + ch * 64) * DD + t;
    #pragma unroll 8
    for (int n = 0; n < 64; n++)
        acc += al[n] * xb[(size_t)n * DD];
    part[(b * 16 + ch) * DD + t] = acc;
}

__global__ void sent_final(const float* __restrict__ part, float* __restrict__ out) {
    int b = blockIdx.x, t = threadIdx.x;
    float s = 0.f;
    #pragma unroll
    for (int c = 0; c < 16; c++) s += part[(b * 16 + c) * DD + t];
    out[b * DD + t] = s;
}

extern "C" void kernel_launch(void* const* d_in, const int* in_sizes, int n_in,
                              void* d_out, int out_size, void* d_ws, size_t ws_size,
                              hipStream_t stream) {
    (void)in_sizes; (void)n_in; (void)out_size; (void)ws_size;
    const float* x  = (const float*)d_in[0];
    const float* w1 = (const float*)d_in[1];
    const float* w2 = (const float*)d_in[2];
    const float* w4 = (const float*)d_in[3];
    float* out = (float*)d_out;

    char* ws = (char*)d_ws;
    const size_t MB = 1024 * 1024;
    unsigned short* qb   = (unsigned short*)(ws);                    // 32 MB
    unsigned short* wt   = (unsigned short*)(ws + 64 * MB);          // 256 KB
    float*          xv   = (float*)(ws + 64 * MB + 256 * 1024);     // 256 KB
    float*          num  = (float*)(ws + 64 * MB + 512 * 1024);     // 1 MB (4 quarters)
    float*          den  = (float*)(ws + 64 * MB + 1536 * 1024);    // 1 MB (4 quarters)
    float*          part = (float*)(ws);   // aliases qb: safe — qb fully rewritten each call

    prep_wt<<<dim3(2 * PP), dim3(DD), 0, stream>>>(w1, w2, wt);
    qk_fused<<<dim3(BB * NN / 256), dim3(512), 0, stream>>>(x, wt, w4, qb, xv);
    attn_logit<<<dim3(4 * BB), dim3(512), 0, stream>>>(x, wt, qb, xv, num, den);
    sent_partial<<<dim3(BB, 16), dim3(256), 0, stream>>>(x, num, den, part);
    sent_final<<<dim3(BB), dim3(DD), 0, stream>>>(part, out);
}

// Round 20
// 95.749 us; speedup vs baseline: 1.0474x; 1.0474x over previous
//
#include <hip/hip_runtime.h>
#include <hip/hip_bf16.h>
#include <cstdint>
#include <cstddef>

constexpr int BB = 64;
constexpr int NN = 1024;
constexpr int DD = 256;
constexpr int PP = 256;

typedef short short8 __attribute__((ext_vector_type(8)));
typedef float f32x4 __attribute__((ext_vector_type(4)));

constexpr float LOG2E = 1.4426950408889634f;

__device__ __forceinline__ unsigned short f2bf(float f) {
    union { __hip_bfloat16 h; unsigned short u; } v;
    v.h = __float2bfloat16(f);
    return v.u;
}

// fast sigmoid: rcp(1 + exp2(-x*log2e))
__device__ __forceinline__ float fsigmoid(float x) {
    return __builtin_amdgcn_rcpf(1.f + __builtin_amdgcn_exp2f(x * -LOG2E));
}

__device__ __forceinline__ void pin8(short8& v) {
    asm volatile("" : "+v"(v));
}

// async global->LDS, 16B per lane, LDS dest = wave-uniform base + lane*16
__device__ __forceinline__ void async_load16(void* lds, const void* g) {
    __builtin_amdgcn_global_load_lds(
        (const __attribute__((address_space(1))) unsigned int*)g,
        (__attribute__((address_space(3))) unsigned int*)lds, 16, 0, 0);
}

// Stage a 256-row x 256-col bf16 tile (128KB) with 8 waves (32 rows/wave).
// XOR-swizzled via pre-swizzled SOURCE (LDS write stays linear).
__device__ __forceinline__ void stage256_w8(const unsigned short* base,
                                            unsigned short* lds, int wv, int lane) {
    char* dst0 = (char*)lds + wv * 16384;
    #pragma unroll
    for (int i = 0; i < 16; i++) {
        int row = wv * 32 + i * 2 + (lane >> 5);
        int blk = (lane & 31) ^ (row & 7);
        async_load16(dst0 + i * 1024, (const char*)base + row * 512 + blk * 16);
    }
}

// Stage a 256-row x 256-col bf16 tile (128KB) with 16 waves (16 rows/wave).
__device__ __forceinline__ void stage256_w16(const unsigned short* base,
                                             unsigned short* lds, int wv, int lane) {
    char* dst0 = (char*)lds + wv * 8192;
    #pragma unroll
    for (int i = 0; i < 8; i++) {
        int row = wv * 16 + i * 2 + (lane >> 5);
        int blk = (lane & 31) ^ (row & 7);
        async_load16(dst0 + i * 1024, (const char*)base + row * 512 + blk * 16);
    }
}

// Read a 16B MFMA fragment from a swizzled tile (row-stride 512B).
__device__ __forceinline__ short8 lds_frag(const unsigned short* lds, int row, int kidx) {
    uint32_t byte = (uint32_t)(row * 512) + (uint32_t)(((kidx ^ (row & 7)) & 31) << 4);
    return *reinterpret_cast<const short8*>(reinterpret_cast<const char*>(lds) + byte);
}

// ---- prep: wt[j][d] = bf16(w[d][j]) for j<256 -> w1, else w2 (transposed, bf16) ----
__global__ void prep_wt(const float* __restrict__ w1, const float* __restrict__ w2,
                        unsigned short* __restrict__ wt) {
    int j = blockIdx.x;        // 0..511
    int d = threadIdx.x;       // 0..255
    const float* w = (j < PP) ? w1 : w2;
    int jj = j & (PP - 1);
    wt[j * DD + d] = f2bf(w[d * PP + jj]);
}

// ---- q,k = sigmoid(x @ W)  +  xv = x @ w4, fused (r18 verbatim) ----
// 512-thr blocks (8 waves), grid 256 = 1 block/CU. W q-half (128KB) staged
// ONCE while x loads into regs (xf[2][8], 32 rows/wave); ONE barrier;
// barrier-free 16-pt sweep; re-stage k-half; sweep k. setprio on MFMA cluster.
__global__ __launch_bounds__(512, 2) void qk_fused(const float* __restrict__ x,
                                                   const unsigned short* __restrict__ wt,
                                                   const float* __restrict__ w4,
                                                   unsigned short* __restrict__ qb,
                                                   unsigned short* __restrict__ kb,
                                                   float* __restrict__ xv) {
    __shared__ __align__(16) unsigned short wl[256 * 256];   // 128KB, swizzled
    const int t = threadIdx.x, wv = t >> 6, lane = t & 63, l15 = lane & 15, l4 = lane >> 4;
    const int rowBase = blockIdx.x * 256 + wv * 32;

    stage256_w8(wt, wl, wv, lane);   // q-half of W

    // hoist x fragments (bf16) + accumulate xv partials (f32) — overlaps stage
    short8 xf[2][8];
    float xvp[2] = {0.f, 0.f};
    #pragma unroll
    for (int kc = 0; kc < 8; kc++) {
        float4 w4a = *reinterpret_cast<const float4*>(w4 + kc * 32 + l4 * 8);
        float4 w4b = *reinterpret_cast<const float4*>(w4 + kc * 32 + l4 * 8 + 4);
        #pragma unroll
        for (int s = 0; s < 2; s++) {
            const float* xr = x + (size_t)(rowBase + s * 16 + l15) * DD + kc * 32 + l4 * 8;
            float4 a = *reinterpret_cast<const float4*>(xr);
            float4 b = *reinterpret_cast<const float4*>(xr + 4);
            xvp[s] += a.x * w4a.x + a.y * w4a.y + a.z * w4a.z + a.w * w4a.w
                    + b.x * w4b.x + b.y * w4b.y + b.z * w4b.z + b.w * w4b.w;
            short8 f;
            f[0] = (short)f2bf(a.x); f[1] = (short)f2bf(a.y);
            f[2] = (short)f2bf(a.z); f[3] = (short)f2bf(a.w);
            f[4] = (short)f2bf(b.x); f[5] = (short)f2bf(b.y);
            f[6] = (short)f2bf(b.z); f[7] = (short)f2bf(b.w);
            xf[s][kc] = f;
        }
    }
    #pragma unroll
    for (int s = 0; s < 2; s++)
        #pragma unroll
        for (int kc = 0; kc < 8; kc++) pin8(xf[s][kc]);
    #pragma unroll
    for (int s = 0; s < 2; s++) {
        xvp[s] += __shfl_xor(xvp[s], 16);
        xvp[s] += __shfl_xor(xvp[s], 32);
        if (l4 == 0) xv[rowBase + s * 16 + l15] = xvp[s];
    }

    __syncthreads();   // q-half of W ready

    #pragma unroll 1
    for (int h = 0; h < 2; h++) {
        if (h == 1) {
            __syncthreads();               // all waves done reading q-half
            stage256_w8(wt + 256 * DD, wl, wv, lane);   // k-half of W
            __syncthreads();               // k-half ready
        }
        unsigned short* outp = h ? kb : qb;
        #pragma unroll 1
        for (int pt = 0; pt < 16; pt++) {
            f32x4 acc0 = {0.f, 0.f, 0.f, 0.f};
            f32x4 acc1 = {0.f, 0.f, 0.f, 0.f};
            __builtin_amdgcn_s_setprio(1);
            #pragma unroll
            for (int kc = 0; kc < 8; kc++) {
                short8 wf = lds_frag(wl, pt * 16 + l15, kc * 4 + l4);
                acc0 = __builtin_amdgcn_mfma_f32_16x16x32_bf16(wf, xf[0][kc], acc0, 0, 0, 0);
                acc1 = __builtin_amdgcn_mfma_f32_16x16x32_bf16(wf, xf[1][kc], acc1, 0, 0, 0);
            }
            __builtin_amdgcn_s_setprio(0);
            // D: col(l15) = x-row, row(l4*4+r) = p-col
            const int pc = pt * 16 + l4 * 4;
            ushort4 pk;
            pk.x = f2bf(fsigmoid(acc0[0]));
            pk.y = f2bf(fsigmoid(acc0[1]));
            pk.z = f2bf(fsigmoid(acc0[2]));
            pk.w = f2bf(fsigmoid(acc0[3]));
            *reinterpret_cast<ushort4*>(outp + (size_t)(rowBase + l15) * PP + pc) = pk;
            pk.x = f2bf(fsigmoid(acc1[0]));
            pk.y = f2bf(fsigmoid(acc1[1]));
            pk.z = f2bf(fsigmoid(acc1[2]));
            pk.w = f2bf(fsigmoid(acc1[3]));
            *reinterpret_cast<ushort4*>(outp + (size_t)(rowBase + 16 + l15) * PP + pc) = pk;
        }
    }
}

// ---- partial logits: num/den over one m-QUARTER for 512 q-rows ----
// 1024-thr blocks (16 waves), grid 512, XCD-PINNED (wg&7 = b%8). K-quarter
// (256 rows, 128KB swizzled) staged ONCE by 16 waves + ONE barrier; each wave
// owns 32 q-rows (qf[2][8] = 64 VGPR -> ~110 live regs, fits the 128-reg tier
// => 4 waves/SIMD, double r18's occupancy). LDS reads/work double (2 MFMA per
// kf vs 4) — trading LDS-pipe work for latency hiding.
__global__ __launch_bounds__(1024, 4) void attn_logit(const unsigned short* __restrict__ qb,
                                                      const unsigned short* __restrict__ kb,
                                                      const float* __restrict__ xv,
                                                      float* __restrict__ numo,
                                                      float* __restrict__ deno) {
    __shared__ __align__(16) unsigned short kq[256 * 256];   // 128KB, swizzled
    __shared__ float xvs[256];
    const int t = threadIdx.x, wv = t >> 6, lane = t & 63, l15 = lane & 15, l4 = lane >> 4;
    // XCD-pinned decode: wg = (b%8) + 8*(qhalf + 2*(quarter + 4*(b/8)))
    const int wg = blockIdx.x;
    const int xcd = wg & 7, r_ = wg >> 3;
    const int qhalf = r_ & 1;
    const int quarter = (r_ >> 1) & 3;
    const int b = (r_ >> 3) * 8 + xcd;
    const unsigned short* kbb = kb + ((size_t)b * NN + quarter * 256) * PP;

    stage256_w16(kbb, kq, wv, lane);
    if (t < 256) xvs[t] = xv[b * NN + quarter * 256 + t];
    __syncthreads();   // the only barrier

    // hoist Q fragments: 32 q-rows per wave
    short8 qf[2][8];
    const int q0 = b * NN + qhalf * 512 + wv * 32;
    #pragma unroll
    for (int s = 0; s < 2; s++) {
        const unsigned short* qrow = qb + (size_t)(q0 + s * 16 + l15) * PP;
        #pragma unroll
        for (int kc = 0; kc < 8; kc++)
            qf[s][kc] = *reinterpret_cast<const short8*>(qrow + kc * 32 + l4 * 8);
    }
    #pragma unroll
    for (int s = 0; s < 2; s++)
        #pragma unroll
        for (int kc = 0; kc < 8; kc++) pin8(qf[s][kc]);

    float den[2][4], num[2][4];
    #pragma unroll
    for (int s = 0; s < 2; s++)
        #pragma unroll
        for (int r = 0; r < 4; r++) { den[s][r] = 0.f; num[s][r] = 0.f; }

    #pragma unroll 8
    for (int mc = 0; mc < 16; mc++) {
        f32x4 a0 = {0.f, 0.f, 0.f, 0.f};
        f32x4 a1 = {0.f, 0.f, 0.f, 0.f};
        __builtin_amdgcn_s_setprio(1);
        #pragma unroll
        for (int kc = 0; kc < 8; kc++) {
            short8 kf = lds_frag(kq, mc * 16 + l15, kc * 4 + l4);
            a0 = __builtin_amdgcn_mfma_f32_16x16x32_bf16(qf[0][kc], kf, a0, 0, 0, 0);
            a1 = __builtin_amdgcn_mfma_f32_16x16x32_bf16(qf[1][kc], kf, a1, 0, 0, 0);
        }
        __builtin_amdgcn_s_setprio(0);
        float xvv = xvs[mc * 16 + l15];
        #pragma unroll
        for (int r = 0; r < 4; r++) {
            // exp(s/16) = exp2(s * 0.0625*log2e); s in (0,16): no max-subtract
            float e0 = __builtin_amdgcn_exp2f(a0[r] * (0.0625f * LOG2E));
            den[0][r] += e0; num[0][r] += e0 * xvv;
            float e1 = __builtin_amdgcn_exp2f(a1[r] * (0.0625f * LOG2E));
            den[1][r] += e1; num[1][r] += e1 * xvv;
        }
    }
    // reduce over the 16 lanes (l15 group) holding different m-columns
    #pragma unroll
    for (int s = 0; s < 2; s++)
        #pragma unroll
        for (int r = 0; r < 4; r++) {
            #pragma unroll
            for (int off = 1; off < 16; off <<= 1) {
                den[s][r] += __shfl_xor(den[s][r], off);
                num[s][r] += __shfl_xor(num[s][r], off);
            }
        }
    if (l15 == 0) {
        #pragma unroll
        for (int s = 0; s < 2; s++)
            #pragma unroll
            for (int r = 0; r < 4; r++) {
                int n = qhalf * 512 + wv * 32 + s * 16 + l4 * 4 + r;
                size_t o = (size_t)quarter * BB * NN + (size_t)b * NN + n;
                numo[o] = num[s][r];
                deno[o] = den[s][r];
            }
    }
}

// ---- sentence partials: merge 4 num/den quarters -> softmax_n -> weighted row sum ----
__global__ __launch_bounds__(256) void sent_partial(const float* __restrict__ x,
                                                    const float* __restrict__ numo,
                                                    const float* __restrict__ deno,
                                                    float* __restrict__ part) {
    __shared__ float al[64];
    __shared__ float redA[4];
    __shared__ float redB[4];
    const int b = blockIdx.x, ch = blockIdx.y;
    const int t = threadIdx.x;
    float l[4];
    #pragma unroll
    for (int i = 0; i < 4; i++) {
        int n = b * NN + t + i * 256;
        float ns = 0.f, ds = 0.f;
        #pragma unroll
        for (int q = 0; q < 4; q++) {
            ns += numo[(size_t)q * BB * NN + n];
            ds += deno[(size_t)q * BB * NN + n];
        }
        l[i] = ns / ds;
    }
    float mx = fmaxf(fmaxf(l[0], l[1]), fmaxf(l[2], l[3]));
    #pragma unroll
    for (int off = 1; off < 64; off <<= 1) mx = fmaxf(mx, __shfl_xor(mx, off));
    if ((t & 63) == 0) redA[t >> 6] = mx;
    __syncthreads();
    mx = fmaxf(fmaxf(redA[0], redA[1]), fmaxf(redA[2], redA[3]));
    float e[4], es = 0.f;
    #pragma unroll
    for (int i = 0; i < 4; i++) { e[i] = __expf(l[i] - mx); es += e[i]; }
    #pragma unroll
    for (int off = 1; off < 64; off <<= 1) es += __shfl_xor(es, off);
    if ((t & 63) == 0) redB[t >> 6] = es;
    __syncthreads();
    float inv = 1.f / (redB[0] + redB[1] + redB[2] + redB[3]);
    int ei = ch >> 2;
    float sel = (ei == 0) ? e[0] : (ei == 1) ? e[1] : (ei == 2) ? e[2] : e[3];
    if ((t >> 6) == (ch & 3)) al[t & 63] = sel * inv;
    __syncthreads();
    float acc = 0.f;
    const float* xb = x + ((size_t)b * NN + ch * 64) * DD + t;
    #pragma unroll 8
    for (int n = 0; n < 64; n++)
        acc += al[n] * xb[(size_t)n * DD];
    part[(b * 16 + ch) * DD + t] = acc;
}

__global__ void sent_final(const float* __restrict__ part, float* __restrict__ out) {
    int b = blockIdx.x, t = threadIdx.x;
    float s = 0.f;
    #pragma unroll
    for (int c = 0; c < 16; c++) s += part[(b * 16 + c) * DD + t];
    out[b * DD + t] = s;
}

extern "C" void kernel_launch(void* const* d_in, const int* in_sizes, int n_in,
                              void* d_out, int out_size, void* d_ws, size_t ws_size,
                              hipStream_t stream) {
    (void)in_sizes; (void)n_in; (void)out_size; (void)ws_size;
    const float* x  = (const float*)d_in[0];
    const float* w1 = (const float*)d_in[1];
    const float* w2 = (const float*)d_in[2];
    const float* w4 = (const float*)d_in[3];
    float* out = (float*)d_out;

    char* ws = (char*)d_ws;
    const size_t MB = 1024 * 1024;
    unsigned short* qb   = (unsigned short*)(ws);                    // 32 MB
    unsigned short* kb   = (unsigned short*)(ws + 32 * MB);          // 32 MB
    unsigned short* wt   = (unsigned short*)(ws + 64 * MB);          // 256 KB
    float*          xv   = (float*)(ws + 64 * MB + 256 * 1024);     // 256 KB
    float*          num  = (float*)(ws + 64 * MB + 512 * 1024);     // 1 MB (4 quarters)
    float*          den  = (float*)(ws + 64 * MB + 1536 * 1024);    // 1 MB (4 quarters)
    float*          part = (float*)(ws);   // aliases qb: safe — qb fully rewritten each call

    prep_wt<<<dim3(2 * PP), dim3(DD), 0, stream>>>(w1, w2, wt);
    qk_fused<<<dim3(BB * NN / 256), dim3(512), 0, stream>>>(x, wt, w4, qb, kb, xv);
    attn_logit<<<dim3(8 * BB), dim3(1024), 0, stream>>>(qb, kb, xv, num, den);
    sent_partial<<<dim3(BB, 16), dim3(256), 0, stream>>>(x, num, den, part);
    sent_final<<<dim3(BB), dim3(DD), 0, stream>>>(part, out);
}

// Round 21
// 93.944 us; speedup vs baseline: 1.0675x; 1.0192x over previous
//
#include <hip/hip_runtime.h>
#include <hip/hip_bf16.h>
#include <cstdint>
#include <cstddef>

constexpr int BB = 64;
constexpr int NN = 1024;
constexpr int DD = 256;
constexpr int PP = 256;

typedef short short8 __attribute__((ext_vector_type(8)));
typedef float f32x4 __attribute__((ext_vector_type(4)));

constexpr float LOG2E = 1.4426950408889634f;
// softmax temperature folded into qb: S_scaled = (q*QSCALE).k -> exp2(S_scaled)
constexpr float QSCALE = 0.0625f * LOG2E;

__device__ __forceinline__ unsigned short f2bf(float f) {
    union { __hip_bfloat16 h; unsigned short u; } v;
    v.h = __float2bfloat16(f);
    return v.u;
}

// fast sigmoid: rcp(1 + exp2(-x*log2e))
__device__ __forceinline__ float fsigmoid(float x) {
    return __builtin_amdgcn_rcpf(1.f + __builtin_amdgcn_exp2f(x * -LOG2E));
}

__device__ __forceinline__ void pin8(short8& v) {
    asm volatile("" : "+v"(v));
}

// async global->LDS, 16B per lane, LDS dest = wave-uniform base + lane*16
__device__ __forceinline__ void async_load16(void* lds, const void* g) {
    __builtin_amdgcn_global_load_lds(
        (const __attribute__((address_space(1))) unsigned int*)g,
        (__attribute__((address_space(3))) unsigned int*)lds, 16, 0, 0);
}

// Stage a 256-row x 256-col bf16 tile (128KB) with 8 waves (32 rows/wave).
// XOR-swizzled via pre-swizzled SOURCE (LDS write stays linear).
__device__ __forceinline__ void stage256_w8(const unsigned short* base,
                                            unsigned short* lds, int wv, int lane) {
    char* dst0 = (char*)lds + wv * 16384;
    #pragma unroll
    for (int i = 0; i < 16; i++) {
        int row = wv * 32 + i * 2 + (lane >> 5);
        int blk = (lane & 31) ^ (row & 7);
        async_load16(dst0 + i * 1024, (const char*)base + row * 512 + blk * 16);
    }
}

// Stage a 256-row x 256-col bf16 tile (128KB) with 16 waves (16 rows/wave).
__device__ __forceinline__ void stage256_w16(const unsigned short* base,
                                             unsigned short* lds, int wv, int lane) {
    char* dst0 = (char*)lds + wv * 8192;
    #pragma unroll
    for (int i = 0; i < 8; i++) {
        int row = wv * 16 + i * 2 + (lane >> 5);
        int blk = (lane & 31) ^ (row & 7);
        async_load16(dst0 + i * 1024, (const char*)base + row * 512 + blk * 16);
    }
}

// Read a 16B MFMA fragment from a swizzled tile (row-stride 512B).
__device__ __forceinline__ short8 lds_frag(const unsigned short* lds, int row, int kidx) {
    uint32_t byte = (uint32_t)(row * 512) + (uint32_t)(((kidx ^ (row & 7)) & 31) << 4);
    return *reinterpret_cast<const short8*>(reinterpret_cast<const char*>(lds) + byte);
}

// ---- prep: wt[j][d] = bf16(w[d][j]) for j<256 -> w1, else w2 (transposed, bf16) ----
__global__ void prep_wt(const float* __restrict__ w1, const float* __restrict__ w2,
                        unsigned short* __restrict__ wt) {
    int j = blockIdx.x;        // 0..511
    int d = threadIdx.x;       // 0..255
    const float* w = (j < PP) ? w1 : w2;
    int jj = j & (PP - 1);
    wt[j * DD + d] = f2bf(w[d * PP + jj]);
}

// ---- q,k = sigmoid(x @ W)  +  xv = x @ w4, fused (r18 verbatim + q pre-scale) ----
// 512-thr blocks (8 waves), grid 256 = 1 block/CU. W q-half (128KB) staged
// ONCE while x loads into regs (xf[2][8], 32 rows/wave); ONE barrier;
// barrier-free 16-pt sweep; re-stage k-half; sweep k. setprio on MFMA cluster.
// q-branch stores sigmoid*QSCALE (temperature folded in) -> attn tail has no mul.
__global__ __launch_bounds__(512, 2) void qk_fused(const float* __restrict__ x,
                                                   const unsigned short* __restrict__ wt,
                                                   const float* __restrict__ w4,
                                                   unsigned short* __restrict__ qb,
                                                   unsigned short* __restrict__ kb,
                                                   float* __restrict__ xv) {
    __shared__ __align__(16) unsigned short wl[256 * 256];   // 128KB, swizzled
    const int t = threadIdx.x, wv = t >> 6, lane = t & 63, l15 = lane & 15, l4 = lane >> 4;
    const int rowBase = blockIdx.x * 256 + wv * 32;

    stage256_w8(wt, wl, wv, lane);   // q-half of W

    // hoist x fragments (bf16) + accumulate xv partials (f32) — overlaps stage
    short8 xf[2][8];
    float xvp[2] = {0.f, 0.f};
    #pragma unroll
    for (int kc = 0; kc < 8; kc++) {
        float4 w4a = *reinterpret_cast<const float4*>(w4 + kc * 32 + l4 * 8);
        float4 w4b = *reinterpret_cast<const float4*>(w4 + kc * 32 + l4 * 8 + 4);
        #pragma unroll
        for (int s = 0; s < 2; s++) {
            const float* xr = x + (size_t)(rowBase + s * 16 + l15) * DD + kc * 32 + l4 * 8;
            float4 a = *reinterpret_cast<const float4*>(xr);
            float4 b = *reinterpret_cast<const float4*>(xr + 4);
            xvp[s] += a.x * w4a.x + a.y * w4a.y + a.z * w4a.z + a.w * w4a.w
                    + b.x * w4b.x + b.y * w4b.y + b.z * w4b.z + b.w * w4b.w;
            short8 f;
            f[0] = (short)f2bf(a.x); f[1] = (short)f2bf(a.y);
            f[2] = (short)f2bf(a.z); f[3] = (short)f2bf(a.w);
            f[4] = (short)f2bf(b.x); f[5] = (short)f2bf(b.y);
            f[6] = (short)f2bf(b.z); f[7] = (short)f2bf(b.w);
            xf[s][kc] = f;
        }
    }
    #pragma unroll
    for (int s = 0; s < 2; s++)
        #pragma unroll
        for (int kc = 0; kc < 8; kc++) pin8(xf[s][kc]);
    #pragma unroll
    for (int s = 0; s < 2; s++) {
        xvp[s] += __shfl_xor(xvp[s], 16);
        xvp[s] += __shfl_xor(xvp[s], 32);
        if (l4 == 0) xv[rowBase + s * 16 + l15] = xvp[s];
    }

    __syncthreads();   // q-half of W ready

    #pragma unroll 1
    for (int h = 0; h < 2; h++) {
        if (h == 1) {
            __syncthreads();               // all waves done reading q-half
            stage256_w8(wt + 256 * DD, wl, wv, lane);   // k-half of W
            __syncthreads();               // k-half ready
        }
        unsigned short* outp = h ? kb : qb;
        const float oscale = h ? 1.f : QSCALE;
        #pragma unroll 1
        for (int pt = 0; pt < 16; pt++) {
            f32x4 acc0 = {0.f, 0.f, 0.f, 0.f};
            f32x4 acc1 = {0.f, 0.f, 0.f, 0.f};
            __builtin_amdgcn_s_setprio(1);
            #pragma unroll
            for (int kc = 0; kc < 8; kc++) {
                short8 wf = lds_frag(wl, pt * 16 + l15, kc * 4 + l4);
                acc0 = __builtin_amdgcn_mfma_f32_16x16x32_bf16(wf, xf[0][kc], acc0, 0, 0, 0);
                acc1 = __builtin_amdgcn_mfma_f32_16x16x32_bf16(wf, xf[1][kc], acc1, 0, 0, 0);
            }
            __builtin_amdgcn_s_setprio(0);
            // D: col(l15) = x-row, row(l4*4+r) = p-col
            const int pc = pt * 16 + l4 * 4;
            ushort4 pk;
            pk.x = f2bf(fsigmoid(acc0[0]) * oscale);
            pk.y = f2bf(fsigmoid(acc0[1]) * oscale);
            pk.z = f2bf(fsigmoid(acc0[2]) * oscale);
            pk.w = f2bf(fsigmoid(acc0[3]) * oscale);
            *reinterpret_cast<ushort4*>(outp + (size_t)(rowBase + l15) * PP + pc) = pk;
            pk.x = f2bf(fsigmoid(acc1[0]) * oscale);
            pk.y = f2bf(fsigmoid(acc1[1]) * oscale);
            pk.z = f2bf(fsigmoid(acc1[2]) * oscale);
            pk.w = f2bf(fsigmoid(acc1[3]) * oscale);
            *reinterpret_cast<ushort4*>(outp + (size_t)(rowBase + 16 + l15) * PP + pc) = pk;
        }
    }
}

// ---- partial logits: num/den over one m-QUARTER for 512 q-rows (r20 + exp2-direct) ----
// 1024-thr blocks (16 waves), grid 512, XCD-PINNED (wg&7 = b%8). K-quarter
// (256 rows, 128KB swizzled) staged ONCE + ONE barrier; wave owns 32 q-rows
// (qf[2][8]); 4 waves/SIMD. Temperature is pre-folded into qb -> exp2(a) direct.
__global__ __launch_bounds__(1024, 4) void attn_logit(const unsigned short* __restrict__ qb,
                                                      const unsigned short* __restrict__ kb,
                                                      const float* __restrict__ xv,
                                                      float* __restrict__ numo,
                                                      float* __restrict__ deno) {
    __shared__ __align__(16) unsigned short kq[256 * 256];   // 128KB, swizzled
    __shared__ float xvs[256];
    const int t = threadIdx.x, wv = t >> 6, lane = t & 63, l15 = lane & 15, l4 = lane >> 4;
    // XCD-pinned decode: wg = (b%8) + 8*(qhalf + 2*(quarter + 4*(b/8)))
    const int wg = blockIdx.x;
    const int xcd = wg & 7, r_ = wg >> 3;
    const int qhalf = r_ & 1;
    const int quarter = (r_ >> 1) & 3;
    const int b = (r_ >> 3) * 8 + xcd;
    const unsigned short* kbb = kb + ((size_t)b * NN + quarter * 256) * PP;

    stage256_w16(kbb, kq, wv, lane);
    if (t < 256) xvs[t] = xv[b * NN + quarter * 256 + t];
    __syncthreads();   // the only barrier

    // hoist Q fragments: 32 q-rows per wave
    short8 qf[2][8];
    const int q0 = b * NN + qhalf * 512 + wv * 32;
    #pragma unroll
    for (int s = 0; s < 2; s++) {
        const unsigned short* qrow = qb + (size_t)(q0 + s * 16 + l15) * PP;
        #pragma unroll
        for (int kc = 0; kc < 8; kc++)
            qf[s][kc] = *reinterpret_cast<const short8*>(qrow + kc * 32 + l4 * 8);
    }
    #pragma unroll
    for (int s = 0; s < 2; s++)
        #pragma unroll
        for (int kc = 0; kc < 8; kc++) pin8(qf[s][kc]);

    float den[2][4], num[2][4];
    #pragma unroll
    for (int s = 0; s < 2; s++)
        #pragma unroll
        for (int r = 0; r < 4; r++) { den[s][r] = 0.f; num[s][r] = 0.f; }

    #pragma unroll 8
    for (int mc = 0; mc < 16; mc++) {
        f32x4 a0 = {0.f, 0.f, 0.f, 0.f};
        f32x4 a1 = {0.f, 0.f, 0.f, 0.f};
        __builtin_amdgcn_s_setprio(1);
        #pragma unroll
        for (int kc = 0; kc < 8; kc++) {
            short8 kf = lds_frag(kq, mc * 16 + l15, kc * 4 + l4);
            a0 = __builtin_amdgcn_mfma_f32_16x16x32_bf16(qf[0][kc], kf, a0, 0, 0, 0);
            a1 = __builtin_amdgcn_mfma_f32_16x16x32_bf16(qf[1][kc], kf, a1, 0, 0, 0);
        }
        __builtin_amdgcn_s_setprio(0);
        float xvv = xvs[mc * 16 + l15];
        #pragma unroll
        for (int r = 0; r < 4; r++) {
            // temperature pre-folded into qb: S_scaled = log2(e)*S/16 -> exp2 direct
            float e0 = __builtin_amdgcn_exp2f(a0[r]);
            den[0][r] += e0; num[0][r] += e0 * xvv;
            float e1 = __builtin_amdgcn_exp2f(a1[r]);
            den[1][r] += e1; num[1][r] += e1 * xvv;
        }
    }
    // reduce over the 16 lanes (l15 group) holding different m-columns
    #pragma unroll
    for (int s = 0; s < 2; s++)
        #pragma unroll
        for (int r = 0; r < 4; r++) {
            #pragma unroll
            for (int off = 1; off < 16; off <<= 1) {
                den[s][r] += __shfl_xor(den[s][r], off);
                num[s][r] += __shfl_xor(num[s][r], off);
            }
        }
    if (l15 == 0) {
        #pragma unroll
        for (int s = 0; s < 2; s++)
            #pragma unroll
            for (int r = 0; r < 4; r++) {
                int n = qhalf * 512 + wv * 32 + s * 16 + l4 * 4 + r;
                size_t o = (size_t)quarter * BB * NN + (size_t)b * NN + n;
                numo[o] = num[s][r];
                deno[o] = den[s][r];
            }
    }
}

// ---- sentence partials: merge 4 num/den quarters -> softmax_n -> weighted row sum ----
__global__ __launch_bounds__(256) void sent_partial(const float* __restrict__ x,
                                                    const float* __restrict__ numo,
                                                    const float* __restrict__ deno,
                                                    float* __restrict__ part) {
    __shared__ float al[64];
    __shared__ float redA[4];
    __shared__ float redB[4];
    const int b = blockIdx.x, ch = blockIdx.y;
    const int t = threadIdx.x;
    float l[4];
    #pragma unroll
    for (int i = 0; i < 4; i++) {
        int n = b * NN + t + i * 256;
        float ns = 0.f, ds = 0.f;
        #pragma unroll
        for (int q = 0; q < 4; q++) {
            ns += numo[(size_t)q * BB * NN + n];
            ds += deno[(size_t)q * BB * NN + n];
        }
        l[i] = ns / ds;
    }
    float mx = fmaxf(fmaxf(l[0], l[1]), fmaxf(l[2], l[3]));
    #pragma unroll
    for (int off = 1; off < 64; off <<= 1) mx = fmaxf(mx, __shfl_xor(mx, off));
    if ((t & 63) == 0) redA[t >> 6] = mx;
    __syncthreads();
    mx = fmaxf(fmaxf(redA[0], redA[1]), fmaxf(redA[2], redA[3]));
    float e[4], es = 0.f;
    #pragma unroll
    for (int i = 0; i < 4; i++) { e[i] = __expf(l[i] - mx); es += e[i]; }
    #pragma unroll
    for (int off = 1; off < 64; off <<= 1) es += __shfl_xor(es, off);
    if ((t & 63) == 0) redB[t >> 6] = es;
    __syncthreads();
    float inv = 1.f / (redB[0] + redB[1] + redB[2] + redB[3]);
    int ei = ch >> 2;
    float sel = (ei == 0) ? e[0] : (ei == 1) ? e[1] : (ei == 2) ? e[2] : e[3];
    if ((t >> 6) == (ch & 3)) al[t & 63] = sel * inv;
    __syncthreads();
    float acc = 0.f;
    const float* xb = x + ((size_t)b * NN + ch * 64) * DD + t;
    #pragma unroll 8
    for (int n = 0; n < 64; n++)
        acc += al[n] * xb[(size_t)n * DD];
    part[(b * 16 + ch) * DD + t] = acc;
}

__global__ void sent_final(const float* __restrict__ part, float* __restrict__ out) {
    int b = blockIdx.x, t = threadIdx.x;
    float s = 0.f;
    #pragma unroll
    for (int c = 0; c < 16; c++) s += part[(b * 16 + c) * DD + t];
    out[b * DD + t] = s;
}

extern "C" void kernel_launch(void* const* d_in, const int* in_sizes, int n_in,
                              void* d_out, int out_size, void* d_ws, size_t ws_size,
                              hipStream_t stream) {
    (void)in_sizes; (void)n_in; (void)out_size; (void)ws_size;
    const float* x  = (const float*)d_in[0];
    const float* w1 = (const float*)d_in[1];
    const float* w2 = (const float*)d_in[2];
    const float* w4 = (const float*)d_in[3];
    float* out = (float*)d_out;

    char* ws = (char*)d_ws;
    const size_t MB = 1024 * 1024;
    unsigned short* qb   = (unsigned short*)(ws);                    // 32 MB
    unsigned short* kb   = (unsigned short*)(ws + 32 * MB);          // 32 MB
    unsigned short* wt   = (unsigned short*)(ws + 64 * MB);          // 256 KB
    float*          xv   = (float*)(ws + 64 * MB + 256 * 1024);     // 256 KB
    float*          num  = (float*)(ws + 64 * MB + 512 * 1024);     // 1 MB (4 quarters)
    float*          den  = (float*)(ws + 64 * MB + 1536 * 1024);    // 1 MB (4 quarters)
    float*          part = (float*)(ws);   // aliases qb: safe — qb fully rewritten each call

    prep_wt<<<dim3(2 * PP), dim3(DD), 0, stream>>>(w1, w2, wt);
    qk_fused<<<dim3(BB * NN / 256), dim3(512), 0, stream>>>(x, wt, w4, qb, kb, xv);
    attn_logit<<<dim3(8 * BB), dim3(1024), 0, stream>>>(qb, kb, xv, num, den);
    sent_partial<<<dim3(BB, 16), dim3(256), 0, stream>>>(x, num, den, part);
    sent_final<<<dim3(BB), dim3(DD), 0, stream>>>(part, out);
}